// Round 1
// baseline (613.097 us; speedup 1.0000x reference)
//
#include <hip/hip_runtime.h>

typedef __attribute__((ext_vector_type(8))) short short8;
typedef __attribute__((ext_vector_type(4))) float f32x4;
typedef __attribute__((ext_vector_type(4))) float fvec4;
typedef __attribute__((ext_vector_type(4))) unsigned int u32x4;
typedef __attribute__((ext_vector_type(4))) unsigned short us4;

#define B_ 8
#define T_ 2048
#define D_ 512

__device__ __forceinline__ unsigned short f2bf(float f) {
    unsigned int u = __float_as_uint(f);
    u += 0x7fffu + ((u >> 16) & 1u);
    return (unsigned short)(u >> 16);
}

// ---------------------------------------------------------------- prep kernels
__global__ __launch_bounds__(256) void prep_convert(const float* __restrict__ in,
                                                    unsigned short* __restrict__ out) {
    const int idx = blockIdx.x * 256 + threadIdx.x;  // grid sized exactly
    fvec4 v = ((const fvec4*)in)[idx];
    us4 o;
    o.x = f2bf(v.x); o.y = f2bf(v.y); o.z = f2bf(v.z); o.w = f2bf(v.w);
    ((us4*)out)[idx] = o;
}

__global__ __launch_bounds__(256) void prep_w(const float* __restrict__ W0, const float* __restrict__ W1,
                                              const float* __restrict__ W2, const float* __restrict__ W3,
                                              unsigned short* __restrict__ T0, unsigned short* __restrict__ T1,
                                              unsigned short* __restrict__ T2, unsigned short* __restrict__ T3) {
    const int o = blockIdx.x * 256 + threadIdx.x;    // 0..262143, write-coalesced
    const int c = o >> 9, r = o & 511;               // WT[c][r] = W[r][c]
    const float* W = (blockIdx.y == 0) ? W0 : (blockIdx.y == 1) ? W1 : (blockIdx.y == 2) ? W2 : W3;
    unsigned short* Tp = (blockIdx.y == 0) ? T0 : (blockIdx.y == 1) ? T1 : (blockIdx.y == 2) ? T2 : T3;
    Tp[o] = f2bf(W[r * 512 + c]);
}

__global__ __launch_bounds__(256) void prep_pe(unsigned short* __restrict__ pe) {
    const int o = blockIdx.x * 256 + threadIdx.x;    // 2048*512 exact
    const int rpos = o >> 9;
    const int c = o & 511;
    const int ci = (c < 256) ? c : c - 256;
    const float sf = -0.03611898183128701f;          // -log(10000)/255
    const float dv = expf((float)ci * sf);
    const float ang = (float)rpos * dv;
    const float v = (c < 256) ? sinf(ang) : cosf(ang);
    pe[o] = f2bf(v);
}

// ---------------------------------------------------------------- BT-GEMM
// C[M,N] = A[M,K] * B[N,K]^T   (both operands row-major bf16-as-ushort)
enum { EPI_F32 = 0, EPI_BF16 = 1, EPI_QCQR = 2, EPI_RADD = 3, EPI_PV = 4, EPI_SCORE = 5 };

template <int EPI>
__global__ __launch_bounds__(256) void btgemm(
    const unsigned short* __restrict__ A,
    const unsigned short* __restrict__ Bm,
    void* __restrict__ C0, void* __restrict__ C1,
    const float* __restrict__ bias0, const float* __restrict__ bias1,
    int K, int lda, int ldb, int ldc,
    long sAz, long sBz, long sCz)
{
    const int i0 = blockIdx.y * 128;
    const int j0 = blockIdx.x * 128;
    if (EPI == EPI_SCORE && j0 > i0) return;                    // fully masked tile
    if (EPI == EPI_RADD && (i0 + j0) < (T_ - 255)) return;      // no valid shift target
    const int z = blockIdx.z;
    A  += (long)z * sAz;
    Bm += (long)z * sBz;
    const int kmax = (EPI == EPI_PV) ? (i0 + 128) : K;          // causal K-limit for PV

    __shared__ __align__(16) unsigned short At[128 * 32];
    __shared__ __align__(16) unsigned short Bt[128 * 32];

    const int tid = threadIdx.x;
    const int wid = tid >> 6;
    const int lane = tid & 63;
    const int quad = lane >> 4;
    const int lr = lane & 15;
    const int wm = (wid & 1) * 64;
    const int wn = (wid >> 1) * 64;

    f32x4 acc[4][4];
#pragma unroll
    for (int r = 0; r < 4; ++r)
#pragma unroll
        for (int c = 0; c < 4; ++c) acc[r][c] = (f32x4){0.f, 0.f, 0.f, 0.f};

    const int sr = tid >> 2;          // staging row 0..63
    const int sc = (tid & 3) * 8;     // staging col (bf16 units)
    const unsigned short* Ag = A + (long)(i0 + sr) * lda + sc;
    const unsigned short* Bg = Bm + (long)(j0 + sr) * ldb + sc;
    unsigned short* Al0 = &At[sr * 32 + sc];
    unsigned short* Al1 = &At[(sr + 64) * 32 + sc];
    unsigned short* Bl0 = &Bt[sr * 32 + sc];
    unsigned short* Bl1 = &Bt[(sr + 64) * 32 + sc];

    for (int kk = 0; kk < kmax; kk += 32) {
        *(u32x4*)Al0 = *(const u32x4*)(Ag + kk);
        *(u32x4*)Al1 = *(const u32x4*)(Ag + 64L * lda + kk);
        *(u32x4*)Bl0 = *(const u32x4*)(Bg + kk);
        *(u32x4*)Bl1 = *(const u32x4*)(Bg + 64L * ldb + kk);
        __syncthreads();
        short8 av[4], bv[4];
#pragma unroll
        for (int r = 0; r < 4; ++r)
            av[r] = *(const short8*)&At[(wm + r * 16 + lr) * 32 + quad * 8];
#pragma unroll
        for (int c = 0; c < 4; ++c)
            bv[c] = *(const short8*)&Bt[(wn + c * 16 + lr) * 32 + quad * 8];
#pragma unroll
        for (int r = 0; r < 4; ++r)
#pragma unroll
            for (int c = 0; c < 4; ++c)
                acc[r][c] = __builtin_amdgcn_mfma_f32_16x16x32_bf16(av[r], bv[c], acc[r][c], 0, 0, 0);
        __syncthreads();
    }

    // epilogue: C/D layout col=lane&15, row=quad*4+reg  [verified m89/m91]
#pragma unroll
    for (int r = 0; r < 4; ++r) {
#pragma unroll
        for (int c = 0; c < 4; ++c) {
            const int gi = i0 + wm + r * 16 + quad * 4;
            const int gj = j0 + wn + c * 16 + lr;
#pragma unroll
            for (int t = 0; t < 4; ++t) {
                const float v = acc[r][c][t];
                const long row = gi + t;
                if (EPI == EPI_QCQR) {
                    ((unsigned short*)C0)[row * ldc + gj] = f2bf(v + bias0[gj]);
                    ((unsigned short*)C1)[row * ldc + gj] = f2bf(v + bias1[gj]);
                } else if (EPI == EPI_BF16) {
                    ((unsigned short*)C0)[(long)z * sCz + row * ldc + gj] = f2bf(v);
                } else if (EPI == EPI_F32 || EPI == EPI_SCORE || EPI == EPI_PV) {
                    ((float*)C0)[(long)z * sCz + row * ldc + gj] = v;
                } else if (EPI == EPI_RADD) {
                    // R[i,p] -> C[i, i+p-(T-1)]  (rel_shift_causal, masked region only)
                    const int j = (int)row + gj - (T_ - 1);
                    if (j >= 0) {
                        float* Cf = (float*)C0 + (long)z * sCz;
                        Cf[row * ldc + j] += v;
                    }
                }
            }
        }
    }
}

// ---------------------------------------------------------------- row softmax
// One block per row; writes P (bf16) in-place over the fp32 score row.
__global__ __launch_bounds__(256) void softmax_rows(float* __restrict__ Cbase) {
    float* Cm = Cbase + (long)blockIdx.y * 4194304L;  // slot stride 2048*2048 f32
    const int i = blockIdx.x;
    const int n = i + 1;
    __shared__ float s[2048];
    __shared__ float red[8];
    const int tid = threadIdx.x;
    const int wid = tid >> 6;
    const float SC = 0.04419417382415922f;            // 1/sqrt(512)
    float* row = Cm + (long)i * 2048;
    float lmax = -3.0e38f;
    for (int j = tid; j < n; j += 256) { float v = row[j] * SC; s[j] = v; lmax = fmaxf(lmax, v); }
    for (int o = 32; o; o >>= 1) lmax = fmaxf(lmax, __shfl_down(lmax, o));
    if ((tid & 63) == 0) red[wid] = lmax;
    __syncthreads();
    if (tid == 0) red[4] = fmaxf(fmaxf(red[0], red[1]), fmaxf(red[2], red[3]));
    __syncthreads();
    const float m = red[4];
    float lsum = 0.f;
    for (int j = tid; j < n; j += 256) { float e = __expf(s[j] - m); s[j] = e; lsum += e; }
    for (int o = 32; o; o >>= 1) lsum += __shfl_down(lsum, o);
    __syncthreads();
    if ((tid & 63) == 0) red[wid] = lsum;
    __syncthreads();
    if (tid == 0) red[4] = 1.0f / (red[0] + red[1] + red[2] + red[3]);
    __syncthreads();
    const float inv = red[4];
    unsigned short* P = (unsigned short*)Cm;          // bf16 row stride 4096
    const int iend = ((i >> 7) + 1) << 7;             // zero-pad to 128-tile edge
    for (int j = tid; j < iend; j += 256) {
        const float pv = (j < n) ? s[j] * inv : 0.f;
        P[(long)i * 4096 + j] = f2bf(pv);
    }
}

// ---------------------------------------------------------------- launcher
extern "C" void kernel_launch(void* const* d_in, const int* in_sizes, int n_in,
                              void* d_out, int out_size, void* d_ws, size_t ws_size,
                              hipStream_t stream) {
    (void)in_sizes; (void)n_in; (void)out_size; (void)ws_size;
    const float* inputs = (const float*)d_in[0];
    const float* Wq = (const float*)d_in[1];
    const float* Wk = (const float*)d_in[2];
    const float* Wv = (const float*)d_in[3];
    const float* Wrel = (const float*)d_in[4];
    const float* cb = (const float*)d_in[5];
    const float* rb = (const float*)d_in[6];
    float* out = (float*)d_out;

    // workspace layout (157 MB total)
    char* ws = (char*)d_ws;
    unsigned short* in_bf = (unsigned short*)ws;            // 16384x512 bf16
    unsigned short* WqT = (unsigned short*)(ws + 16777216);
    unsigned short* WkT = WqT + 262144;
    unsigned short* WvT = WkT + 262144;
    unsigned short* WrT = WvT + 262144;
    unsigned short* pe  = WrT + 262144;                     // 2048x512
    unsigned short* qc  = pe + 1048576;                     // 16384x512
    unsigned short* qr  = qc + 8388608;
    unsigned short* kbf = qr + 8388608;
    unsigned short* vT  = kbf + 8388608;                    // 8 x (512x2048)
    unsigned short* rk  = vT + 8388608;                     // 2048x512
    float* C4 = (float*)(rk + 1048576);                     // 4 x 2048x2048 f32

    prep_convert<<<dim3(8192), 256, 0, stream>>>(inputs, in_bf);
    prep_w<<<dim3(1024, 4), 256, 0, stream>>>(Wq, Wk, Wv, Wrel, WqT, WkT, WvT, WrT);
    prep_pe<<<dim3(4096), 256, 0, stream>>>(pe);

    const long TD = (long)T_ * D_;
    const long DT = (long)D_ * T_;
    // qc/qr = in @ Wq + biases
    btgemm<EPI_QCQR><<<dim3(4, 128, 1), 256, 0, stream>>>(in_bf, WqT, qc, qr, cb, rb,
                                                          512, 512, 512, 512, 0, 0, 0);
    // k = in @ Wk
    btgemm<EPI_BF16><<<dim3(4, 128, 1), 256, 0, stream>>>(in_bf, WkT, kbf, nullptr, nullptr, nullptr,
                                                          512, 512, 512, 512, 0, 0, 0);
    // vT[b] = Wv^T @ in[b]^T   (M=512, N=2048 per batch)
    btgemm<EPI_BF16><<<dim3(16, 4, 8), 256, 0, stream>>>(WvT, in_bf, vT, nullptr, nullptr, nullptr,
                                                         512, 512, 512, 2048, 0, TD, DT);
    // rk = pe @ Wrel
    btgemm<EPI_BF16><<<dim3(4, 16, 1), 256, 0, stream>>>(pe, WrT, rk, nullptr, nullptr, nullptr,
                                                         512, 512, 512, 512, 0, 0, 0);

    for (int g = 0; g < 2; ++g) {   // 4 batches per group (score buffer = 4 slots)
        const unsigned short* qcg = qc + (long)g * 4 * TD;
        const unsigned short* qrg = qr + (long)g * 4 * TD;
        const unsigned short* kg  = kbf + (long)g * 4 * TD;
        // content scores (causal tiles only)
        btgemm<EPI_SCORE><<<dim3(16, 16, 4), 256, 0, stream>>>(qcg, kg, C4, nullptr, nullptr, nullptr,
                                                               512, 512, 512, 2048, TD, TD, 4194304L);
        // relative scores, shift-scatter-added into C
        btgemm<EPI_RADD><<<dim3(16, 16, 4), 256, 0, stream>>>(qrg, rk, C4, nullptr, nullptr, nullptr,
                                                              512, 512, 512, 2048, TD, 0, 4194304L);
        // softmax -> P (bf16, in place)
        softmax_rows<<<dim3(2048, 4), 256, 0, stream>>>(C4);
        // out = P @ V (via vT), causal K-limit per row-tile
        btgemm<EPI_PV><<<dim3(4, 16, 4), 256, 0, stream>>>((unsigned short*)C4, vT + (long)g * 4 * DT,
                                                           out + (long)g * 4 * TD, nullptr, nullptr, nullptr,
                                                           2048, 4096, 2048, 512, 8388608L, DT, TD);
    }
}

// Round 2
// 598.074 us; speedup vs baseline: 1.0251x; 1.0251x over previous
//
#include <hip/hip_runtime.h>

typedef __attribute__((ext_vector_type(8))) short short8;
typedef __attribute__((ext_vector_type(4))) float f32x4;
typedef __attribute__((ext_vector_type(4))) float fvec4;
typedef __attribute__((ext_vector_type(4))) unsigned int u32x4;
typedef __attribute__((ext_vector_type(4))) unsigned short us4;

#define B_ 8
#define T_ 2048
#define D_ 512

__device__ __forceinline__ unsigned short f2bf(float f) {
    unsigned int u = __float_as_uint(f);
    u += 0x7fffu + ((u >> 16) & 1u);
    return (unsigned short)(u >> 16);
}

// async global->LDS, 16B per lane; LDS dest is wave-uniform base + lane*16
__device__ __forceinline__ void gload16(const void* g, void* l) {
    __builtin_amdgcn_global_load_lds((const __attribute__((address_space(1))) unsigned int*)g,
                                     (__attribute__((address_space(3))) unsigned int*)l,
                                     16, 0, 0);
}

// ---------------------------------------------------------------- prep kernels
__global__ __launch_bounds__(256) void prep_convert(const float* __restrict__ in,
                                                    unsigned short* __restrict__ out) {
    const int idx = blockIdx.x * 256 + threadIdx.x;  // grid sized exactly
    fvec4 v = ((const fvec4*)in)[idx];
    us4 o;
    o.x = f2bf(v.x); o.y = f2bf(v.y); o.z = f2bf(v.z); o.w = f2bf(v.w);
    ((us4*)out)[idx] = o;
}

__global__ __launch_bounds__(256) void prep_w(const float* __restrict__ W0, const float* __restrict__ W1,
                                              const float* __restrict__ W2, const float* __restrict__ W3,
                                              unsigned short* __restrict__ T0, unsigned short* __restrict__ T1,
                                              unsigned short* __restrict__ T2, unsigned short* __restrict__ T3) {
    const int o = blockIdx.x * 256 + threadIdx.x;    // 0..262143, write-coalesced
    const int c = o >> 9, r = o & 511;               // WT[c][r] = W[r][c]
    const float* W = (blockIdx.y == 0) ? W0 : (blockIdx.y == 1) ? W1 : (blockIdx.y == 2) ? W2 : W3;
    unsigned short* Tp = (blockIdx.y == 0) ? T0 : (blockIdx.y == 1) ? T1 : (blockIdx.y == 2) ? T2 : T3;
    Tp[o] = f2bf(W[r * 512 + c]);
}

__global__ __launch_bounds__(256) void prep_pe(unsigned short* __restrict__ pe) {
    const int o = blockIdx.x * 256 + threadIdx.x;    // 2048*512 exact
    const int rpos = o >> 9;
    const int c = o & 511;
    const int ci = (c < 256) ? c : c - 256;
    const float sf = -0.03611898183128701f;          // -log(10000)/255
    const float dv = expf((float)ci * sf);
    const float ang = (float)rpos * dv;
    const float v = (c < 256) ? sinf(ang) : cosf(ang);
    pe[o] = f2bf(v);
}

// ---------------------------------------------------------------- BT-GEMM
// C[M,N] = A[M,K] * B[N,K]^T   (both operands row-major bf16-as-ushort)
enum { EPI_F32 = 0, EPI_BF16 = 1, EPI_QCQR = 2, EPI_RADD = 3, EPI_PV = 4, EPI_SCORE = 5 };
#define SC_ 0.04419417382415922f                     // 1/sqrt(512)

template <int EPI>
__global__ __launch_bounds__(256) void btgemm(
    const unsigned short* __restrict__ A,
    const unsigned short* __restrict__ Bm,
    void* __restrict__ C0, void* __restrict__ C1,
    const float* __restrict__ bias0, const float* __restrict__ bias1,
    int K, int lda, int ldb, int ldc,
    long sAz, long sBz, long sCz)
{
    const int i0 = blockIdx.y * 128;
    const int j0 = blockIdx.x * 128;
    if (EPI == EPI_SCORE && j0 > i0) return;                    // fully masked tile
    if (EPI == EPI_RADD && (i0 + j0) < (T_ - 255)) return;      // no valid shift target
    const int z = blockIdx.z;
    A  += (long)z * sAz;
    Bm += (long)z * sBz;
    const int kmax = (EPI == EPI_PV) ? (i0 + 128) : K;          // causal K-limit for PV

    __shared__ __align__(16) unsigned short At[128 * 32];
    __shared__ __align__(16) unsigned short Bt[128 * 32];

    const int tid = threadIdx.x;
    const int wid = tid >> 6;
    const int lane = tid & 63;
    const int quad = lane >> 4;
    const int lr = lane & 15;
    const int wm = (wid & 1) * 64;
    const int wn = (wid >> 1) * 64;

    f32x4 acc[4][4];
#pragma unroll
    for (int r = 0; r < 4; ++r)
#pragma unroll
        for (int c = 0; c < 4; ++c) acc[r][c] = (f32x4){0.f, 0.f, 0.f, 0.f};

    const int sr = tid >> 2;          // staging row 0..63
    const int sc = (tid & 3) * 8;     // staging col (bf16 units)
    const unsigned short* Ag = A + (long)(i0 + sr) * lda + sc;
    const unsigned short* Bg = Bm + (long)(j0 + sr) * ldb + sc;
    // LDS byte offset of thread's 16B slot = tid*16 -> wave-uniform base + lane*16
    unsigned short* lA0 = &At[wid * 512];
    unsigned short* lA1 = &At[2048 + wid * 512];
    unsigned short* lB0 = &Bt[wid * 512];
    unsigned short* lB1 = &Bt[2048 + wid * 512];

    for (int kk = 0; kk < kmax; kk += 32) {
        gload16(Ag + kk, lA0);
        gload16(Ag + 64L * lda + kk, lA1);
        gload16(Bg + kk, lB0);
        gload16(Bg + 64L * ldb + kk, lB1);
        __syncthreads();   // drains vmcnt(0): LDS data visible
        short8 av[4], bv[4];
#pragma unroll
        for (int r = 0; r < 4; ++r)
            av[r] = *(const short8*)&At[(wm + r * 16 + lr) * 32 + quad * 8];
#pragma unroll
        for (int c = 0; c < 4; ++c)
            bv[c] = *(const short8*)&Bt[(wn + c * 16 + lr) * 32 + quad * 8];
#pragma unroll
        for (int r = 0; r < 4; ++r)
#pragma unroll
            for (int c = 0; c < 4; ++c)
                acc[r][c] = __builtin_amdgcn_mfma_f32_16x16x32_bf16(av[r], bv[c], acc[r][c], 0, 0, 0);
        __syncthreads();
    }

    // epilogue: C/D layout col=lane&15, row=quad*4+reg  [verified m89/m91]
#pragma unroll
    for (int r = 0; r < 4; ++r) {
#pragma unroll
        for (int c = 0; c < 4; ++c) {
            const int gi = i0 + wm + r * 16 + quad * 4;
            const int gj = j0 + wn + c * 16 + lr;
#pragma unroll
            for (int t = 0; t < 4; ++t) {
                const float v = acc[r][c][t];
                const long row = gi + t;
                if (EPI == EPI_QCQR) {
                    ((unsigned short*)C0)[row * ldc + gj] = f2bf(v + bias0[gj]);
                    ((unsigned short*)C1)[row * ldc + gj] = f2bf(v + bias1[gj]);
                } else if (EPI == EPI_BF16) {
                    ((unsigned short*)C0)[(long)z * sCz + row * ldc + gj] = f2bf(v);
                } else if (EPI == EPI_SCORE) {
                    ((float*)C0)[(long)z * sCz + row * ldc + gj] = v * SC_;  // scale folded in
                } else if (EPI == EPI_F32 || EPI == EPI_PV) {
                    ((float*)C0)[(long)z * sCz + row * ldc + gj] = v;
                } else if (EPI == EPI_RADD) {
                    // R[i,p] -> C[i, i+p-(T-1)]  (rel_shift_causal, masked region only)
                    const int j = (int)row + gj - (T_ - 1);
                    if (j >= 0) {
                        float* Cf = (float*)C0 + (long)z * sCz;
                        Cf[row * ldc + j] += v * SC_;
                    }
                }
            }
        }
    }
}

// ---------------------------------------------------------------- row softmax
// One block per row; writes P (bf16) in-place over the fp32 score row.
// Scores arrive pre-scaled by 1/sqrt(D).
__global__ __launch_bounds__(256) void softmax_rows(float* __restrict__ Cbase) {
    float* Cm = Cbase + (long)blockIdx.y * 4194304L;  // slot stride 2048*2048 f32
    const int i = blockIdx.x;
    const int n = i + 1;
    __shared__ float s[2048];
    __shared__ float red[8];
    const int tid = threadIdx.x;
    const int wid = tid >> 6;
    float* row = Cm + (long)i * 2048;
    float lmax = -3.0e38f;
    for (int j = tid; j < n; j += 256) { float v = row[j]; s[j] = v; lmax = fmaxf(lmax, v); }
    for (int o = 32; o; o >>= 1) lmax = fmaxf(lmax, __shfl_down(lmax, o));
    if ((tid & 63) == 0) red[wid] = lmax;
    __syncthreads();
    if (tid == 0) red[4] = fmaxf(fmaxf(red[0], red[1]), fmaxf(red[2], red[3]));
    __syncthreads();
    const float m = red[4];
    float lsum = 0.f;
    for (int j = tid; j < n; j += 256) { float e = __expf(s[j] - m); s[j] = e; lsum += e; }
    for (int o = 32; o; o >>= 1) lsum += __shfl_down(lsum, o);
    __syncthreads();
    if ((tid & 63) == 0) red[wid] = lsum;
    __syncthreads();
    if (tid == 0) red[4] = 1.0f / (red[0] + red[1] + red[2] + red[3]);
    __syncthreads();
    const float inv = red[4];
    unsigned short* P = (unsigned short*)Cm;          // bf16 row stride 4096
    const int iend = ((i >> 7) + 1) << 7;             // zero-pad to 128-tile edge
    for (int j = tid; j < iend; j += 256) {
        const float pv = (j < n) ? s[j] * inv : 0.f;
        P[(long)i * 4096 + j] = f2bf(pv);
    }
}

// ---------------------------------------------------------------- launcher
extern "C" void kernel_launch(void* const* d_in, const int* in_sizes, int n_in,
                              void* d_out, int out_size, void* d_ws, size_t ws_size,
                              hipStream_t stream) {
    (void)in_sizes; (void)n_in; (void)out_size; (void)ws_size;
    const float* inputs = (const float*)d_in[0];
    const float* Wq = (const float*)d_in[1];
    const float* Wk = (const float*)d_in[2];
    const float* Wv = (const float*)d_in[3];
    const float* Wrel = (const float*)d_in[4];
    const float* cb = (const float*)d_in[5];
    const float* rb = (const float*)d_in[6];
    float* out = (float*)d_out;

    // workspace layout (157 MB total)
    char* ws = (char*)d_ws;
    unsigned short* in_bf = (unsigned short*)ws;            // 16384x512 bf16
    unsigned short* WqT = (unsigned short*)(ws + 16777216);
    unsigned short* WkT = WqT + 262144;
    unsigned short* WvT = WkT + 262144;
    unsigned short* WrT = WvT + 262144;
    unsigned short* pe  = WrT + 262144;                     // 2048x512
    unsigned short* qc  = pe + 1048576;                     // 16384x512
    unsigned short* qr  = qc + 8388608;
    unsigned short* kbf = qr + 8388608;
    unsigned short* vT  = kbf + 8388608;                    // 8 x (512x2048)
    unsigned short* rk  = vT + 8388608;                     // 2048x512
    float* C4 = (float*)(rk + 1048576);                     // 4 x 2048x2048 f32

    prep_convert<<<dim3(8192), 256, 0, stream>>>(inputs, in_bf);
    prep_w<<<dim3(1024, 4), 256, 0, stream>>>(Wq, Wk, Wv, Wrel, WqT, WkT, WvT, WrT);
    prep_pe<<<dim3(4096), 256, 0, stream>>>(pe);

    const long TD = (long)T_ * D_;
    const long DT = (long)D_ * T_;
    // qc/qr = in @ Wq + biases
    btgemm<EPI_QCQR><<<dim3(4, 128, 1), 256, 0, stream>>>(in_bf, WqT, qc, qr, cb, rb,
                                                          512, 512, 512, 512, 0, 0, 0);
    // k = in @ Wk
    btgemm<EPI_BF16><<<dim3(4, 128, 1), 256, 0, stream>>>(in_bf, WkT, kbf, nullptr, nullptr, nullptr,
                                                          512, 512, 512, 512, 0, 0, 0);
    // vT[b] = Wv^T @ in[b]^T   (M=512, N=2048 per batch)
    btgemm<EPI_BF16><<<dim3(16, 4, 8), 256, 0, stream>>>(WvT, in_bf, vT, nullptr, nullptr, nullptr,
                                                         512, 512, 512, 2048, 0, TD, DT);
    // rk = pe @ Wrel
    btgemm<EPI_BF16><<<dim3(4, 16, 1), 256, 0, stream>>>(pe, WrT, rk, nullptr, nullptr, nullptr,
                                                         512, 512, 512, 512, 0, 0, 0);

    for (int g = 0; g < 2; ++g) {   // 4 batches per group (score buffer = 4 slots)
        const unsigned short* qcg = qc + (long)g * 4 * TD;
        const unsigned short* qrg = qr + (long)g * 4 * TD;
        const unsigned short* kg  = kbf + (long)g * 4 * TD;
        // content scores (causal tiles only), pre-scaled
        btgemm<EPI_SCORE><<<dim3(16, 16, 4), 256, 0, stream>>>(qcg, kg, C4, nullptr, nullptr, nullptr,
                                                               512, 512, 512, 2048, TD, TD, 4194304L);
        // relative scores, shift-scatter-added into C, pre-scaled
        btgemm<EPI_RADD><<<dim3(16, 16, 4), 256, 0, stream>>>(qrg, rk, C4, nullptr, nullptr, nullptr,
                                                              512, 512, 512, 2048, TD, 0, 4194304L);
        // softmax -> P (bf16, in place)
        softmax_rows<<<dim3(2048, 4), 256, 0, stream>>>(C4);
        // out = P @ V (via vT), causal K-limit per row-tile
        btgemm<EPI_PV><<<dim3(4, 16, 4), 256, 0, stream>>>((unsigned short*)C4, vT + (long)g * 4 * DT,
                                                           out + (long)g * 4 * TD, nullptr, nullptr, nullptr,
                                                           2048, 4096, 2048, 512, 8388608L, DT, TD);
    }
}